// Round 19
// baseline (1164.161 us; speedup 1.0000x reference)
//
#include <hip/hip_runtime.h>
#include <math.h>

// ---------------------------------------------------------------------------
// FeatureEncoder R37 = R36 (1160us) with L1 reverted to single-pixel
// conv3s2_f4. R36 counters split the verdict: 2px/thread REGRESSED L1
// (148 -> 181-189us, FETCH 29.8->35.7MB, occ 37->22%) but gained ~40us on
// L2/L3 (weight-dominated: CIN=64/128 vs L1's 32; L1 is input-BW-heavy and
// paid for the wider 66-col input footprint). Keep the mechanism where the
// weight stream dominates, revert where input dominates:
// - L1: conv3s2_f4 single-pixel (R31-proven, 148us, 4096 blocks)
// - L2/L3: conv3s2_f4x2 2px/thread (R36)
// - L4-L6: convt3_x2 2px/thread (R33/R34-proven)
// - L0/L7: conv7 LDS-staged (R25-proven)
// ---------------------------------------------------------------------------

#define IDIV(a, b) (((a) + (b) - 1) / (b))

__device__ __forceinline__ int reflect_i(int i, int n) {
    i = i < 0 ? -i : i;
    return i >= n ? 2 * n - 2 - i : i;
}

__device__ __forceinline__ float ldb(const char* base, int boff) {
    return *(const float*)(base + boff);
}

// block-level (sum,sumsq) reduction for OCPT channels -> partial store
template <int OCPT>
__device__ __forceinline__ void stats_block_store(
    const float* sv, const float* ssv, float* __restrict__ spart,
    float* __restrict__ sspart, int P, int tile, int pc0) {
    __shared__ float redS[OCPT], redSS[OCPT];
    if (threadIdx.x < OCPT) { redS[threadIdx.x] = 0.f; redSS[threadIdx.x] = 0.f; }
    __syncthreads();
    int lane = threadIdx.x & 63;
#pragma unroll
    for (int j = 0; j < OCPT; ++j) {
        float s = sv[j], ss = ssv[j];
#pragma unroll
        for (int o = 32; o > 0; o >>= 1) {
            s += __shfl_down(s, o);
            ss += __shfl_down(ss, o);
        }
        if (lane == 0) { atomicAdd(&redS[j], s); atomicAdd(&redSS[j], ss); }  // LDS atomics
    }
    __syncthreads();
    if (threadIdx.x < OCPT) {
        spart[(size_t)tile * P + pc0 + threadIdx.x] = redS[threadIdx.x];
        sspart[(size_t)tile * P + pc0 + threadIdx.x] = redSS[threadIdx.x];
    }
}

// fold [nT][P] partials -> mean, inv (one wavefront per plane)
__global__ __launch_bounds__(64) void stat_reduce_mi(
    const float* __restrict__ sp, const float* __restrict__ ssp,
    float* __restrict__ mean, float* __restrict__ inv, int P, int nT,
    float rcp_plane) {
    int p = blockIdx.x;
    float a = 0.f, bsum = 0.f;
    for (int t = threadIdx.x; t < nT; t += 64) {
        a += sp[(size_t)t * P + p];
        bsum += ssp[(size_t)t * P + p];
    }
#pragma unroll
    for (int o = 32; o > 0; o >>= 1) {
        a += __shfl_down(a, o);
        bsum += __shfl_down(bsum, o);
    }
    if (threadIdx.x == 0) {
        float m = a * rcp_plane;
        float var = bsum * rcp_plane - m * m;
        mean[p] = m;
        inv[p] = rsqrtf(var + 1e-5f);
    }
}

// ---------------- 7x7 same-conv (L0), LDS-staged tile, fused stats ----------
template <int CIN, int OCPT>
__global__ __launch_bounds__(256) void conv7_lds(
    const float* __restrict__ x, const float* __restrict__ w,
    const float* __restrict__ b, float* __restrict__ y,
    float* __restrict__ spart, float* __restrict__ sspart, int P,
    int Cout, int H, int W) {
    constexpr int TR = 22, TC = 22, RS = 24;
    __shared__ float s[CIN][TR][RS];
    int tx = threadIdx.x & 15, ty = threadIdx.x >> 4;
    int tilesX = W / 16;
    int bx = blockIdx.x % tilesX, by = blockIdx.x / tilesX;
    int oh0 = by * 16, ow0 = bx * 16;
    int oc0 = blockIdx.y * OCPT;
    int n = blockIdx.z;
    const float* xn = x + (size_t)n * CIN * H * W;

    for (int q = threadIdx.x; q < CIN * TR * TC; q += 256) {
        int p = q / (TR * TC), rem = q % (TR * TC);
        int r = rem / TC, c = rem % TC;
        int ih = reflect_i(oh0 + r - 3, H);
        int iw = reflect_i(ow0 + c - 3, W);
        s[p][r][c] = xn[(size_t)p * H * W + (size_t)ih * W + iw];
    }
    __syncthreads();

    float acc[OCPT];
#pragma unroll
    for (int j = 0; j < OCPT; ++j) acc[j] = 0.f;

    for (int ic = 0; ic < CIN; ++ic) {
        const float* wp = w + ((size_t)oc0 * CIN + ic) * 49;
#pragma unroll
        for (int kh = 0; kh < 7; ++kh) {
#pragma unroll
            for (int kw = 0; kw < 7; ++kw) {
                float vt = s[ic][ty + kh][tx + kw];
#pragma unroll
                for (int j = 0; j < OCPT; ++j)
                    acc[j] += vt * wp[(size_t)j * CIN * 49 + kh * 7 + kw];
            }
        }
    }

    int oh = oh0 + ty, ow = ow0 + tx;
    float sv[OCPT], ssv[OCPT];
#pragma unroll
    for (int j = 0; j < OCPT; ++j) {
        float r = acc[j] + b[oc0 + j];
        y[(((size_t)n * Cout + oc0 + j) * H + oh) * W + ow] = r;
        sv[j] = r;
        ssv[j] = r * r;
    }
    stats_block_store<OCPT>(sv, ssv, spart, sspart, P, blockIdx.x, n * Cout + oc0);
}

// ---------------- 7x7 conv, ic-split partial (L7), LDS-staged ---------------
template <int CINTOT, int ICPB, int OCPT>
__global__ __launch_bounds__(256) void conv7_part_lds(
    const float* __restrict__ x, const float* __restrict__ w,
    float* __restrict__ part, size_t PS, int H, int W) {
    constexpr int TR = 22, TC = 22, RS = 24;
    __shared__ float s[ICPB][TR][RS];
    int tx = threadIdx.x & 15, ty = threadIdx.x >> 4;
    int tilesX = IDIV(W, 16);
    int bx = blockIdx.x % tilesX, by = blockIdx.x / tilesX;
    int oh0 = by * 16, ow0 = bx * 16;
    int ks = blockIdx.y;
    int n = blockIdx.z;
    const int ic0 = ks * ICPB;
    const float* xn = x + (size_t)n * CINTOT * H * W;

    for (int q = threadIdx.x; q < ICPB * TR * TC; q += 256) {
        int p = q / (TR * TC), rem = q % (TR * TC);
        int r = rem / TC, c = rem % TC;
        int ih = reflect_i(oh0 + r - 3, H);
        int iw = reflect_i(ow0 + c - 3, W);
        s[p][r][c] = xn[(size_t)(ic0 + p) * H * W + (size_t)ih * W + iw];
    }
    __syncthreads();

    float acc[OCPT];
#pragma unroll
    for (int j = 0; j < OCPT; ++j) acc[j] = 0.f;

#pragma unroll
    for (int icl = 0; icl < ICPB; ++icl) {
        const float* wp = w + (size_t)(ic0 + icl) * 49;
#pragma unroll
        for (int kh = 0; kh < 7; ++kh) {
#pragma unroll
            for (int kw = 0; kw < 7; ++kw) {
                float vt = s[icl][ty + kh][tx + kw];
#pragma unroll
                for (int j = 0; j < OCPT; ++j)
                    acc[j] += vt * wp[(size_t)j * CINTOT * 49 + kh * 7 + kw];
            }
        }
    }

    int oh = oh0 + ty, ow = ow0 + tx;
    if (oh < H && ow < W) {
#pragma unroll
        for (int j = 0; j < OCPT; ++j)
            part[(size_t)ks * PS + (((size_t)n * OCPT + j) * H + oh) * W + ow] = acc[j];
    }
}

// ---------------- 3x3 s2 conv, single-pixel f4 rows (L1), fused stats -------
template <int CIN, int ICB, int OCPT>
__global__ __launch_bounds__(256) void conv3s2_f4(
    const float* __restrict__ x, const float* __restrict__ w,
    const float* __restrict__ b, float* __restrict__ y,
    float* __restrict__ spart, float* __restrict__ sspart, int P,
    int Cout, int Hin, int Win, int Hout, int Wout) {
    int tx = threadIdx.x & 15, ty = threadIdx.x >> 4;
    int tilesX = Wout >> 4;
    int ow = (blockIdx.x % tilesX) * 16 + tx;
    int oh = (blockIdx.x / tilesX) * 16 + ty;
    int oc0 = blockIdx.y * OCPT;
    int n = blockIdx.z;

    int iw0 = ow * 2 - 1;
    bool shb = iw0 < 0;                 // only ow==0 lanes
    int cb = shb ? 0 : iw0;             // clamped base col, in [0, Win-3]
    int ih0 = oh * 2 - 1;
    int rof[3];
    float mr[3];
#pragma unroll
    for (int kh = 0; kh < 3; ++kh) {
        int ih = ih0 + kh;
        int ihc = min(max(ih, 0), Hin - 1);
        rof[kh] = (ihc * Win + cb) * 4;
        mr[kh] = (ih >= 0 && ih < Hin) ? 1.f : 0.f;
    }

    float acc[OCPT];
#pragma unroll
    for (int j = 0; j < OCPT; ++j) acc[j] = 0.f;

    const char* xb = (const char*)x + (size_t)n * CIN * Hin * Win * 4;
    const int HWb = Hin * Win * 4;

    for (int ic0 = 0; ic0 < CIN; ic0 += ICB) {
        float t[ICB][9];
#pragma unroll
        for (int icl = 0; icl < ICB; ++icl) {
            const char* xp = xb + (size_t)(ic0 + icl) * HWb;  // uniform advance
#pragma unroll
            for (int kh = 0; kh < 3; ++kh) {
                float4 v = *(const float4*)(xp + rof[kh]);
                float e0 = shb ? 0.f : v.x;
                float e1 = shb ? v.x : v.y;
                float e2 = shb ? v.y : v.z;
                t[icl][kh * 3 + 0] = e0 * mr[kh];
                t[icl][kh * 3 + 1] = e1 * mr[kh];
                t[icl][kh * 3 + 2] = e2 * mr[kh];
            }
        }
#pragma unroll
        for (int icl = 0; icl < ICB; ++icl) {
            const float* wp = w + ((size_t)oc0 * CIN + ic0 + icl) * 9;
#pragma unroll
            for (int j = 0; j < OCPT; ++j) {
                const float* wj = wp + (size_t)j * CIN * 9;
                float4 wa = *(const float4*)wj;
                float4 wb = *(const float4*)(wj + 4);
                float w8 = wj[8];
                acc[j] += t[icl][0] * wa.x + t[icl][1] * wa.y + t[icl][2] * wa.z +
                          t[icl][3] * wa.w + t[icl][4] * wb.x + t[icl][5] * wb.y +
                          t[icl][6] * wb.z + t[icl][7] * wb.w + t[icl][8] * w8;
            }
        }
    }
    float sv[OCPT], ssv[OCPT];
#pragma unroll
    for (int j = 0; j < OCPT; ++j) {
        float r = acc[j] + b[oc0 + j];
        y[(((size_t)n * Cout + oc0 + j) * Hout + oh) * Wout + ow] = r;
        sv[j] = r;
        ssv[j] = r * r;
    }
    stats_block_store<OCPT>(sv, ssv, spart, sspart, P, blockIdx.x, n * Cout + oc0);
}

// ---------------- 3x3 s2 conv, 2px/thread (ow, ow+16), shared weights -------
// L2/L3: weight-dominated layers. Requires Wout % 32 == 0 (exact grid).
template <int CIN, int ICB, int OCPT>
__global__ __launch_bounds__(256) void conv3s2_f4x2(
    const float* __restrict__ x, const float* __restrict__ w,
    const float* __restrict__ b, float* __restrict__ y,
    float* __restrict__ spart, float* __restrict__ sspart, int P,
    int Cout, int Hin, int Win, int Hout, int Wout) {
    int tx = threadIdx.x & 15, ty = threadIdx.x >> 4;
    int tilesX = Wout >> 5;
    int bx = blockIdx.x % tilesX, by = blockIdx.x / tilesX;
    int oh = by * 16 + ty;
    int oc0 = blockIdx.y * OCPT;
    int n = blockIdx.z;

    int ows[2];
    ows[0] = bx * 32 + tx;
    ows[1] = ows[0] + 16;

    int ih0 = oh * 2 - 1;
    float mr[3];
    int rbase[3];
#pragma unroll
    for (int kh = 0; kh < 3; ++kh) {
        int ih = ih0 + kh;
        int ihc = min(max(ih, 0), Hin - 1);
        rbase[kh] = ihc * Win;
        mr[kh] = (ih >= 0 && ih < Hin) ? 1.f : 0.f;
    }
    bool shbp[2];
    int rof[2][3];
#pragma unroll
    for (int p = 0; p < 2; ++p) {
        int iw0 = ows[p] * 2 - 1;
        bool shb = iw0 < 0;            // only possible for p==0, ow==0
        int cb = shb ? 0 : iw0;
        shbp[p] = shb;
#pragma unroll
        for (int kh = 0; kh < 3; ++kh) rof[p][kh] = (rbase[kh] + cb) * 4;
    }

    float acc[2][OCPT];
#pragma unroll
    for (int p = 0; p < 2; ++p)
#pragma unroll
        for (int j = 0; j < OCPT; ++j) acc[p][j] = 0.f;

    const char* xb = (const char*)x + (size_t)n * CIN * Hin * Win * 4;
    const int HWb = Hin * Win * 4;

    for (int ic0 = 0; ic0 < CIN; ic0 += ICB) {
        float t[ICB][2][9];
#pragma unroll
        for (int icl = 0; icl < ICB; ++icl) {
            const char* xp = xb + (size_t)(ic0 + icl) * HWb;  // uniform advance
#pragma unroll
            for (int p = 0; p < 2; ++p) {
#pragma unroll
                for (int kh = 0; kh < 3; ++kh) {
                    float4 v = *(const float4*)(xp + rof[p][kh]);
                    float e0 = shbp[p] ? 0.f : v.x;
                    float e1 = shbp[p] ? v.x : v.y;
                    float e2 = shbp[p] ? v.y : v.z;
                    t[icl][p][kh * 3 + 0] = e0 * mr[kh];
                    t[icl][p][kh * 3 + 1] = e1 * mr[kh];
                    t[icl][p][kh * 3 + 2] = e2 * mr[kh];
                }
            }
        }
#pragma unroll
        for (int icl = 0; icl < ICB; ++icl) {
            const float* wp = w + ((size_t)oc0 * CIN + ic0 + icl) * 9;
#pragma unroll
            for (int j = 0; j < OCPT; ++j) {
                const float* wj = wp + (size_t)j * CIN * 9;
                float4 wa = *(const float4*)wj;
                float4 wb = *(const float4*)(wj + 4);
                float w8 = wj[8];
#pragma unroll
                for (int p = 0; p < 2; ++p) {
                    acc[p][j] += t[icl][p][0] * wa.x + t[icl][p][1] * wa.y +
                                 t[icl][p][2] * wa.z + t[icl][p][3] * wa.w +
                                 t[icl][p][4] * wb.x + t[icl][p][5] * wb.y +
                                 t[icl][p][6] * wb.z + t[icl][p][7] * wb.w +
                                 t[icl][p][8] * w8;
                }
            }
        }
    }
    float sv[OCPT], ssv[OCPT];
#pragma unroll
    for (int j = 0; j < OCPT; ++j) {
        float bb = b[oc0 + j];
        float s = 0.f, ss = 0.f;
#pragma unroll
        for (int p = 0; p < 2; ++p) {
            float r = acc[p][j] + bb;
            y[(((size_t)n * Cout + oc0 + j) * Hout + oh) * Wout + ows[p]] = r;
            s += r; ss += r * r;
        }
        sv[j] = s; ssv[j] = ss;
    }
    stats_block_store<OCPT>(sv, ssv, spart, sspart, P, blockIdx.x, n * Cout + oc0);
}

// ---------------- convT, 2 pixels/thread (qx, qx+16), shared weights --------
template <int CIN, int ICB, int OCPT>
__global__ __launch_bounds__(256) void convt3_x2(
    const float* __restrict__ x, const float* __restrict__ w,
    const float* __restrict__ b, float* __restrict__ y,
    float* __restrict__ spart, float* __restrict__ sspart, int P,
    int Cout, int Hin, int Win, int Hout, int Wout) {
    int tx = threadIdx.x & 15, ty = threadIdx.x >> 4;
    int tilesX = IDIV(Win, 32);
    int bx = blockIdx.x % tilesX, by = blockIdx.x / tilesX;
    int qy = by * 16 + ty;
    int oc0 = blockIdx.y * OCPT;
    int n = blockIdx.z;

    int qxs[2];
    qxs[0] = bx * 32 + tx;
    qxs[1] = qxs[0] + 16;
    bool vldp[2], xinp[2], yinp[2];
    int p00[2], p10[2];
    float m01[2], m10[2], m11[2];
#pragma unroll
    for (int p = 0; p < 2; ++p) {
        bool valid = (qxs[p] < Win) && (qy < Hin);
        int qxc = min(qxs[p], Win - 1), qyc = min(qy, Hin - 1);
        bool xin = valid && (qxs[p] + 1 < Win);
        bool yin = valid && (qy + 1 < Hin);
        vldp[p] = valid; xinp[p] = xin; yinp[p] = yin;
        int o10 = yin ? Win : 0;
        m01[p] = xin ? 1.f : 0.f;
        m10[p] = yin ? 1.f : 0.f;
        m11[p] = m01[p] * m10[p];
        p00[p] = (qyc * Win + qxc) * 4;
        p10[p] = p00[p] + o10 * 4;
    }

    float a00[2][OCPT], a01[2][OCPT], a10[2][OCPT], a11[2][OCPT];
#pragma unroll
    for (int p = 0; p < 2; ++p)
#pragma unroll
        for (int j = 0; j < OCPT; ++j) {
            a00[p][j] = a01[p][j] = a10[p][j] = a11[p][j] = 0.f;
        }

    const char* xb = (const char*)x + (size_t)n * CIN * Hin * Win * 4;  // uniform
    const int HWb = Hin * Win * 4;

    float va[ICB][2][4], vb[ICB][2][4];
    auto load = [&](float (&v)[ICB][2][4], int ic0) {
#pragma unroll
        for (int icl = 0; icl < ICB; ++icl) {
            const char* xp = xb + (size_t)(ic0 + icl) * HWb;  // uniform advance
#pragma unroll
            for (int p = 0; p < 2; ++p) {
                float2 u = *(const float2*)(xp + p00[p]);
                float2 d = *(const float2*)(xp + p10[p]);
                v[icl][p][0] = u.x;
                v[icl][p][1] = u.y * m01[p];
                v[icl][p][2] = d.x * m10[p];
                v[icl][p][3] = d.y * m11[p];
            }
        }
    };
    auto fma = [&](const float (&v)[ICB][2][4], int ic0) {
#pragma unroll
        for (int icl = 0; icl < ICB; ++icl) {
            const float* wp = w + ((size_t)(ic0 + icl) * Cout + oc0) * 9;
#pragma unroll
            for (int j = 0; j < OCPT; ++j) {
                const float* wj = wp + j * 9;
                float4 wa = *(const float4*)wj;        // w0 w1 w2 w3
                float4 wb = *(const float4*)(wj + 4);  // w4 w5 w6 w7
                float w8 = wj[8];
#pragma unroll
                for (int p = 0; p < 2; ++p) {
                    a00[p][j] += wb.x * v[icl][p][0];
                    a01[p][j] += wb.y * v[icl][p][0] + wa.w * v[icl][p][1];
                    a10[p][j] += wb.w * v[icl][p][0] + wa.y * v[icl][p][2];
                    a11[p][j] += w8 * v[icl][p][0] + wb.z * v[icl][p][1] +
                                 wa.z * v[icl][p][2] + wa.x * v[icl][p][3];
                }
            }
        }
    };

    load(va, 0);
    for (int ic0 = 0; ic0 < CIN; ic0 += 2 * ICB) {
        load(vb, ic0 + ICB);
        fma(va, ic0);
        load(va, min(ic0 + 2 * ICB, CIN - ICB));
        fma(vb, ic0 + ICB);
    }

    int oh = 2 * qy;
    float sv[OCPT], ssv[OCPT];
#pragma unroll
    for (int j = 0; j < OCPT; ++j) {
        float s = 0.f, ss = 0.f;
        float bb = b[oc0 + j];
#pragma unroll
        for (int p = 0; p < 2; ++p) {
            if (vldp[p]) {
                int ow = 2 * qxs[p];
                float* yp = y + (((size_t)n * Cout + oc0 + j) * Hout + oh) * Wout + ow;
                float t00 = a00[p][j] + bb;
                yp[0] = t00; s += t00; ss += t00 * t00;
                if (xinp[p]) { float t = a01[p][j] + bb; yp[1] = t; s += t; ss += t * t; }
                if (yinp[p]) { float t = a10[p][j] + bb; yp[Wout] = t; s += t; ss += t * t; }
                if (xinp[p] && yinp[p]) {
                    float t = a11[p][j] + bb;
                    yp[Wout + 1] = t; s += t; ss += t * t;
                }
            }
        }
        sv[j] = s; ssv[j] = ss;
    }
    stats_block_store<OCPT>(sv, ssv, spart, sspart, P, blockIdx.x, n * Cout + oc0);
}

// ---------------- inorm apply, float4 coalesced (plane % 4 == 0) ------------
__global__ void inorm_apply4(float* __restrict__ x, const float* __restrict__ mean,
                             const float* __restrict__ inv, int plane4) {
    int pc = blockIdx.y;
    int i = blockIdx.x * 256 + threadIdx.x;
    if (i >= plane4) return;
    float m = mean[pc], iv = inv[pc];
    float4* p = (float4*)(x + (size_t)pc * plane4 * 4);
    float4 v = p[i];
    v.x = fmaxf(0.f, (v.x - m) * iv);
    v.y = fmaxf(0.f, (v.y - m) * iv);
    v.z = fmaxf(0.f, (v.z - m) * iv);
    v.w = fmaxf(0.f, (v.w - m) * iv);
    p[i] = v;
}

// ---------------- inorm apply, 1 elem/thread coalesced (any plane) ----------
__global__ void inorm_apply1(float* __restrict__ x, const float* __restrict__ mean,
                             const float* __restrict__ inv, int plane) {
    int pc = blockIdx.y;
    int i = blockIdx.x * 256 + threadIdx.x;
    if (i >= plane) return;
    float m = mean[pc], iv = inv[pc];
    size_t idx = (size_t)pc * plane + i;
    x[idx] = fmaxf(0.f, (x[idx] - m) * iv);
}

// ---------------- segment mean (accum fused with L7 finalize) ---------------
__global__ void seg_zero(float* __restrict__ bins) {
    if (threadIdx.x < 128) bins[threadIdx.x] = 0.f;
}

// reads the 4 ic-split partials + bias, computes tanh inline; a7 never built.
__global__ void seg_accum_f(const float* __restrict__ part, const float* __restrict__ b,
                            const int* __restrict__ inst, float* __restrict__ bins,
                            int HW, size_t PS) {
    __shared__ float ls[128];  // 96 sums + 32 counts
    for (int i = threadIdx.x; i < 128; i += 256) ls[i] = 0.f;
    __syncthreads();
    int n = blockIdx.y;
    int i = blockIdx.x * 256 + threadIdx.x;
    if (i < HW) {
        int id = inst[(size_t)n * HW + i];
#pragma unroll
        for (int c = 0; c < 3; ++c) {
            size_t off = ((size_t)(n * 3 + c)) * HW + i;
            float v = part[off] + part[PS + off] + part[2 * PS + off] +
                      part[3 * PS + off] + b[c];
            atomicAdd(&ls[id * 3 + c], tanhf(v));
        }
        atomicAdd(&ls[96 + id], 1.0f);
    }
    __syncthreads();
    for (int i2 = threadIdx.x; i2 < 128; i2 += 256)
        if (ls[i2] != 0.f) atomicAdd(&bins[i2], ls[i2]);
}

__global__ void seg_scatter(const float* __restrict__ bins, const int* __restrict__ inst,
                            float* __restrict__ out, int HW) {
    int n = blockIdx.y;
    int i = blockIdx.x * 256 + threadIdx.x;
    if (i >= HW) return;
    int id = inst[(size_t)n * HW + i];
    float c = fmaxf(bins[96 + id], 1.0f);
    out[((size_t)n * 3 + 0) * HW + i] = bins[id * 3 + 0] / c;
    out[((size_t)n * 3 + 1) * HW + i] = bins[id * 3 + 1] / c;
    out[((size_t)n * 3 + 2) * HW + i] = bins[id * 3 + 2] / c;
}

// ---------------------------------------------------------------------------
extern "C" void kernel_launch(void* const* d_in, const int* in_sizes, int n_in,
                              void* d_out, int out_size, void* d_ws, size_t ws_size,
                              hipStream_t stream) {
    const float* x = (const float*)d_in[0];
    const int* inst = (const int*)d_in[1];
    const float* W[8];
    const float* B[8];
    for (int i = 0; i < 8; ++i) {
        W[i] = (const float*)d_in[2 + 2 * i];
        B[i] = (const float*)d_in[3 + 2 * i];
    }
    float* ws = (float*)d_ws;

    // End-aligned ping-pong arena (R2/R6 proven)
    const size_t S = 25165824;  // floats
    float* a0 = ws;                  // [8,32,256,256]
    float* a1 = ws + 16777216;       // [8,64,128,128]
    float* a2 = ws;                  // [8,128,64,64]
    float* a3 = ws + 23068672;       // [8,256,32,32]
    float* a4 = ws;                  // [8,128,63,63]
    float* a5 = ws + 17165824;       // [8,64,125,125]
    float* a6 = ws;                  // [8,32,249,249]  0 .. 15.87M
    float* PART = ws + 16000000;     // 4 x 1488024 floats (gap above a6)
    float* mean = ws + S;            // 2048
    float* inv = mean + 2048;        // 2048
    float* bins = inv + 2048;        // 128
    float* spart = bins + 128;       // 65536 (max nT*P = 256*256)
    float* sspart = spart + 65536;   // 65536

    // L0: 7x7 reflect, 3->32, 256. LDS-staged, OCPT=8, 8192 blocks
    conv7_lds<3, 8><<<dim3(256, 4, 8), 256, 0, stream>>>(
        x, W[0], B[0], a0, spart, sspart, 256, 32, 256, 256);
    stat_reduce_mi<<<dim3(256), 64, 0, stream>>>(spart, sspart, mean, inv, 256, 256, 1.f / 65536.f);
    inorm_apply4<<<dim3(IDIV(16384, 256), 256), 256, 0, stream>>>(a0, mean, inv, 16384);

    // L1: 3x3 s2, 32->64, 256->128. SINGLE-pixel f4 (input-BW layer), 4096 blocks
    conv3s2_f4<32, 2, 8><<<dim3(64, 8, 8), 256, 0, stream>>>(
        a0, W[1], B[1], a1, spart, sspart, 512, 64, 256, 256, 128, 128);
    stat_reduce_mi<<<dim3(512), 64, 0, stream>>>(spart, sspart, mean, inv, 512, 64, 1.f / 16384.f);
    inorm_apply4<<<dim3(IDIV(4096, 256), 512), 256, 0, stream>>>(a1, mean, inv, 4096);

    // L2: 3x3 s2, 64->128, 128->64. 2px/thread, 1024 blocks (8 tiles)
    conv3s2_f4x2<64, 2, 8><<<dim3(8, 16, 8), 256, 0, stream>>>(
        a1, W[2], B[2], a2, spart, sspart, 1024, 128, 128, 128, 64, 64);
    stat_reduce_mi<<<dim3(1024), 64, 0, stream>>>(spart, sspart, mean, inv, 1024, 8, 1.f / 4096.f);
    inorm_apply4<<<dim3(IDIV(1024, 256), 1024), 256, 0, stream>>>(a2, mean, inv, 1024);

    // L3: 3x3 s2, 128->256, 64->32. 2px/thread, 512 blocks (2 tiles)
    conv3s2_f4x2<128, 2, 8><<<dim3(2, 32, 8), 256, 0, stream>>>(
        a2, W[3], B[3], a3, spart, sspart, 2048, 256, 64, 64, 32, 32);
    stat_reduce_mi<<<dim3(2048), 64, 0, stream>>>(spart, sspart, mean, inv, 2048, 2, 1.f / 1024.f);
    inorm_apply4<<<dim3(1, 2048), 256, 0, stream>>>(a3, mean, inv, 256);

    // L4: convT, 256->128, 32->63. 2px/thread, 512 blocks (2 tiles)
    convt3_x2<256, 2, 4><<<dim3(2, 32, 8), 256, 0, stream>>>(
        a3, W[4], B[4], a4, spart, sspart, 1024, 128, 32, 32, 63, 63);
    stat_reduce_mi<<<dim3(1024), 64, 0, stream>>>(spart, sspart, mean, inv, 1024, 2, 1.f / 3969.f);
    inorm_apply1<<<dim3(IDIV(3969, 256), 1024), 256, 0, stream>>>(a4, mean, inv, 3969);

    // L5: convT, 128->64, 63->125. 2px/thread, 1024 blocks (8 tiles)
    convt3_x2<128, 2, 4><<<dim3(8, 16, 8), 256, 0, stream>>>(
        a4, W[5], B[5], a5, spart, sspart, 512, 64, 63, 63, 125, 125);
    stat_reduce_mi<<<dim3(512), 64, 0, stream>>>(spart, sspart, mean, inv, 512, 8, 1.f / 15625.f);
    inorm_apply1<<<dim3(IDIV(15625, 256), 512), 256, 0, stream>>>(a5, mean, inv, 15625);

    // L6: convT, 64->32, 125->249. 2px/thread, 2048 blocks (32 tiles)
    convt3_x2<64, 2, 4><<<dim3(32, 8, 8), 256, 0, stream>>>(
        a5, W[6], B[6], a6, spart, sspart, 256, 32, 125, 125, 249, 249);
    stat_reduce_mi<<<dim3(256), 64, 0, stream>>>(spart, sspart, mean, inv, 256, 32, 1.f / 62001.f);
    inorm_apply1<<<dim3(IDIV(62001, 256), 256), 256, 0, stream>>>(a6, mean, inv, 62001);

    // L7: 7x7 reflect, 32->3, 249 — ic-split x4, LDS-staged
    conv7_part_lds<32, 8, 3><<<dim3(256, 4, 8), 256, 0, stream>>>(
        a6, W[7], PART, 1488024, 249, 249);

    // segment mean (accum reads partials + bias + tanh inline)
    seg_zero<<<1, 128, 0, stream>>>(bins);
    seg_accum_f<<<dim3(IDIV(62001, 256), 8), 256, 0, stream>>>(
        PART, B[7], inst, bins, 62001, 1488024);
    seg_scatter<<<dim3(IDIV(62001, 256), 8), 256, 0, stream>>>(bins, inst, (float*)d_out, 62001);
}